// Round 2
// baseline (414.763 us; speedup 1.0000x reference)
//
#include <hip/hip_runtime.h>

// E3TAOBackflow on MI355X.
// Key reduction: antisymmetrization makes the scalar output exactly 0 and the
// vector output equal to layer0's gated vector fed through the purely-linear
// layer1 vector path:  out_v = (v @ [Wh0@Wu0]) * sigmoid(sm) @ (Wh1@Wu1@W1)/sqrt(S)
// where sm = [s, ||v@Wh0||_t] @ Wm0 + bm0.
// Wm1, bm1, W0 are dead. Output dtype: FLOAT32 (reference returns f32).

#define SDIM 128
#define RPB 8          // rows per block
#define MPR (3 * RPB)  // "a-rows" = (row, t) pairs per block

// ---- precompute: Wcat = [Wh0 | Wh0@Wu0] (128x256), T = Wh1@Wu1 (128x128)
__global__ __launch_bounds__(128) void prep1(
    const float* __restrict__ Wh0, const float* __restrict__ Wu0,
    const float* __restrict__ Wh1, const float* __restrict__ Wu1,
    float* __restrict__ Wcat, float* __restrict__ T) {
  int b = blockIdx.x, o = threadIdx.x;
  if (b < 128) {
    int m = b;
    float acc = 0.f;
    for (int h = 0; h < 128; ++h) acc += Wh0[m * 128 + h] * Wu0[h * 128 + o];
    Wcat[m * 256 + o] = Wh0[m * 128 + o];
    Wcat[m * 256 + 128 + o] = acc;
  } else {
    int m = b - 128;
    float acc = 0.f;
    for (int h = 0; h < 128; ++h) acc += Wh1[m * 128 + h] * Wu1[h * 128 + o];
    T[m * 128 + o] = acc;
  }
}

// ---- precompute: C = T @ W1 * (1/sqrt(128))  (128x256)
__global__ __launch_bounds__(256) void prep2(
    const float* __restrict__ T, const float* __restrict__ W1,
    float* __restrict__ C) {
  int m = blockIdx.x, n = threadIdx.x;
  float acc = 0.f;
  for (int h = 0; h < 128; ++h) acc += T[m * 128 + h] * W1[h * 256 + n];
  C[m * 256 + n] = acc * 0.08838834764831845f;  // 1/sqrt(128)
}

// ---- main fused kernel
__global__ __launch_bounds__(256) void main_k(
    const float* __restrict__ x, const float* __restrict__ Wm0,
    const float* __restrict__ bm0, const float* __restrict__ Wcat,
    const float* __restrict__ C, float* __restrict__ out) {
  __shared__ float xs[RPB][SDIM];      // scalar inputs           4 KB
  __shared__ float xv[MPR][SDIM];      // v transposed (r,t)[m]  12 KB
  __shared__ float out1[MPR][256];     // [Vh0 | Vu0] -> v1|vo   24 KB
  __shared__ float vns[RPB][SDIM];     // vector norms            4 KB
  __shared__ float gs[RPB][SDIM];      // sigmoid gate            4 KB

  const int tid = threadIdx.x;
  const int r0 = blockIdx.x * RPB;
  const float* xrow = x + (size_t)r0 * 512;

  // stage x: 8 rows x 512 floats; transpose v into (r,t)-major
  for (int i = 0; i < 4; ++i) {
    int q = tid + 256 * i;          // float4 index, 1024 total
    int r = q >> 7;
    int c4 = (q & 127) << 2;
    float4 v4 = *(const float4*)(xrow + r * 512 + c4);
    float vv[4] = {v4.x, v4.y, v4.z, v4.w};
#pragma unroll
    for (int e = 0; e < 4; ++e) {
      int c = c4 + e;
      if (c < 128) xs[r][c] = vv[e];
      else {
        int cc = c - 128;
        xv[3 * r + cc % 3][cc / 3] = vv[e];
      }
    }
  }
  __syncthreads();

  const int wave = tid >> 6;
  const int lane = tid & 63;
  const int n0 = lane * 4;    // 4 output columns per thread, covers 256
  const int ar0 = wave * 6;   // 6 a-rows per wave

  // phase1: out1[ar][n] = sum_k xv[ar][k] * Wcat[k][n]   (Vh0 | Vu0)
  {
    float acc[6][4];
#pragma unroll
    for (int a = 0; a < 6; ++a)
#pragma unroll
      for (int j = 0; j < 4; ++j) acc[a][j] = 0.f;
    for (int k = 0; k < 128; k += 4) {
      float4 w[4];
#pragma unroll
      for (int kk = 0; kk < 4; ++kk)
        w[kk] = *(const float4*)(Wcat + (size_t)(k + kk) * 256 + n0);
#pragma unroll
      for (int a = 0; a < 6; ++a) {
        float4 xa = *(const float4*)(&xv[ar0 + a][k]);
        float xq[4] = {xa.x, xa.y, xa.z, xa.w};
#pragma unroll
        for (int kk = 0; kk < 4; ++kk) {
          acc[a][0] += xq[kk] * w[kk].x;
          acc[a][1] += xq[kk] * w[kk].y;
          acc[a][2] += xq[kk] * w[kk].z;
          acc[a][3] += xq[kk] * w[kk].w;
        }
      }
    }
#pragma unroll
    for (int a = 0; a < 6; ++a)
      *(float4*)(&out1[ar0 + a][n0]) =
          make_float4(acc[a][0], acc[a][1], acc[a][2], acc[a][3]);
  }
  __syncthreads();

  // phase2a: vn[r][h] = sqrt(sum_t Vh0^2 + eps)
  for (int i = 0; i < 4; ++i) {
    int e = tid + 256 * i;  // 1024
    int r = e >> 7, h = e & 127;
    float a0 = out1[3 * r + 0][h], a1 = out1[3 * r + 1][h],
          a2 = out1[3 * r + 2][h];
    vns[r][h] = sqrtf(a0 * a0 + a1 * a1 + a2 * a2 + 1e-8f);
  }
  __syncthreads();

  // phase2b: sm = [s, vn] @ Wm0 + bm0 ; gate = sigmoid(sm)
  {
    int o = tid & 127;
    int rbase = (tid >> 7) * 4;
    float b = bm0[o];
    float acc[4] = {b, b, b, b};
    for (int k = 0; k < 128; ++k) {
      float wv = Wm0[(size_t)k * 128 + o];
#pragma unroll
      for (int rr = 0; rr < 4; ++rr) acc[rr] += xs[rbase + rr][k] * wv;
    }
    for (int k = 0; k < 128; ++k) {
      float wv = Wm0[(size_t)(128 + k) * 128 + o];
#pragma unroll
      for (int rr = 0; rr < 4; ++rr) acc[rr] += vns[rbase + rr][k] * wv;
    }
#pragma unroll
    for (int rr = 0; rr < 4; ++rr)
      gs[rbase + rr][o] = 1.f / (1.f + __expf(-acc[rr]));
  }
  __syncthreads();

  // phase2c: v1[ar][o] = Vu0[ar][o] * gate[r][o]  (into first half of out1)
  for (int i = 0; i < 12; ++i) {
    int e = tid + 256 * i;  // 3072
    int a = e >> 7, o = e & 127;
    out1[a][o] = out1[a][128 + o] * gs[a / 3][o];
  }
  __syncthreads();

  // phase3: vo[ar][n] = sum_k v1[ar][k] * C[k][n]
  {
    float acc[6][4];
#pragma unroll
    for (int a = 0; a < 6; ++a)
#pragma unroll
      for (int j = 0; j < 4; ++j) acc[a][j] = 0.f;
    for (int k = 0; k < 128; k += 4) {
      float4 w[4];
#pragma unroll
      for (int kk = 0; kk < 4; ++kk)
        w[kk] = *(const float4*)(C + (size_t)(k + kk) * 256 + n0);
#pragma unroll
      for (int a = 0; a < 6; ++a) {
        float4 xa = *(const float4*)(&out1[ar0 + a][k]);
        float xq[4] = {xa.x, xa.y, xa.z, xa.w};
#pragma unroll
        for (int kk = 0; kk < 4; ++kk) {
          acc[a][0] += xq[kk] * w[kk].x;
          acc[a][1] += xq[kk] * w[kk].y;
          acc[a][2] += xq[kk] * w[kk].z;
          acc[a][3] += xq[kk] * w[kk].w;
        }
      }
    }
    __syncthreads();  // everyone done reading out1 as A
#pragma unroll
    for (int a = 0; a < 6; ++a)
      *(float4*)(&out1[ar0 + a][n0]) =
          make_float4(acc[a][0], acc[a][1], acc[a][2], acc[a][3]);
  }
  __syncthreads();

  // epilogue: per row 1024 f32 = 16 groups of [16 zeros | 48 vo interleaved].
  // group g, j>=16: jj=j-16, n=g*16+jj/3, t=jj%3, val=vo[(r,t)][n].
  // float4-vectorized: 256 float4 per row; sub<4 of each 16-float4 group = 0.
  float* orow = out + (size_t)r0 * 1024;
  for (int i = 0; i < 8; ++i) {
    int e = tid + 256 * i;  // float4 index within block, 2048 total
    int r = e >> 8;         // local row
    int q4 = e & 255;       // float4 index within row
    int g = q4 >> 4, sub = q4 & 15;
    float4 val = make_float4(0.f, 0.f, 0.f, 0.f);
    if (sub >= 4) {
      float f[4];
#pragma unroll
      for (int ee = 0; ee < 4; ++ee) {
        int jj = sub * 4 + ee - 16;  // [0,48)
        int n = g * 16 + jj / 3;
        int t = jj - 3 * (jj / 3);
        f[ee] = out1[3 * r + t][n];
      }
      val = make_float4(f[0], f[1], f[2], f[3]);
    }
    *(float4*)(orow + (size_t)r * 1024 + q4 * 4) = val;
  }
}

extern "C" void kernel_launch(void* const* d_in, const int* in_sizes, int n_in,
                              void* d_out, int out_size, void* d_ws,
                              size_t ws_size, hipStream_t stream) {
  const float* mo = (const float*)d_in[0];
  const float* Wh0 = (const float*)d_in[1];
  const float* Wu0 = (const float*)d_in[2];
  const float* Wm0 = (const float*)d_in[3];
  const float* bm0 = (const float*)d_in[4];
  const float* Wh1 = (const float*)d_in[5];
  const float* Wu1 = (const float*)d_in[6];
  // d_in[7]=Wm1, d_in[8]=bm1, d_in[9]=W0: dead code under antisymmetrization
  const float* W1 = (const float*)d_in[10];

  float* ws = (float*)d_ws;
  float* Wcat = ws;           // 128*256
  float* C = ws + 32768;      // 128*256
  float* T = ws + 65536;      // 128*128

  prep1<<<256, 128, 0, stream>>>(Wh0, Wu0, Wh1, Wu1, Wcat, T);
  prep2<<<128, 256, 0, stream>>>(T, W1, C);

  const int R = 2048 * 16;  // 32768 rows
  main_k<<<R / RPB, 256, 0, stream>>>(mo, Wm0, bm0, Wcat, C, (float*)d_out);
}

// Round 3
// 246.420 us; speedup vs baseline: 1.6832x; 1.6832x over previous
//
#include <hip/hip_runtime.h>

// E3TAOBackflow on MI355X — MFMA bf16 version.
// Reduction (verified in R2): antisymmetrization => scalar output exactly 0,
// vector output = (v @ [Wh0@Wu0]) * sigmoid([s,||v@Wh0||] @ Wm0 + bm0) @ C,
// C = Wh1@Wu1@W1/sqrt(S).  Wm1, bm1, W0 dead.  Output dtype f32.
// All three GEMMs via mfma_f32_16x16x32_bf16; weights pre-swizzled to
// fragment-contiguous layout (frag = (nt*KT+kt), lane-major, 8 bf16/lane).

typedef __attribute__((ext_vector_type(8))) short short8;
typedef __attribute__((ext_vector_type(4))) float floatx4;

static __device__ __forceinline__ unsigned short f2bf(float f) {
  unsigned u = __float_as_uint(f);
  u = (u + 0x7fffu + ((u >> 16) & 1u)) >> 16;  // RNE
  return (unsigned short)u;
}
static __device__ __forceinline__ float bf2f(unsigned short h) {
  return __uint_as_float(((unsigned)h) << 16);
}

// write element B[k][n] into swizzled fragment layout (KT = K/32)
static __device__ __forceinline__ void put_sw(unsigned short* B, int k, int n,
                                              float val, int KT) {
  int kt = k >> 5, quad = (k >> 3) & 3, j = k & 7;
  int nt = n >> 4, c = n & 15;
  int lane = quad * 16 + c;
  B[(((nt * KT + kt) * 64 + lane) << 3) + j] = f2bf(val);
}

// ---- prep1: Wcat = [Wh0 | Wh0@Wu0] -> Wcat_sw (128x256, KT=4); T = Wh1@Wu1
__global__ __launch_bounds__(128) void prep1(
    const float* __restrict__ Wh0, const float* __restrict__ Wu0,
    const float* __restrict__ Wh1, const float* __restrict__ Wu1,
    unsigned short* __restrict__ Wcat_sw, float* __restrict__ T) {
  int b = blockIdx.x, o = threadIdx.x;
  if (b < 128) {
    int m = b;
    float acc = 0.f;
    for (int h = 0; h < 128; ++h) acc += Wh0[m * 128 + h] * Wu0[h * 128 + o];
    put_sw(Wcat_sw, m, o, Wh0[m * 128 + o], 4);
    put_sw(Wcat_sw, m, o + 128, acc, 4);
  } else {
    int m = b - 128;
    float acc = 0.f;
    for (int h = 0; h < 128; ++h) acc += Wh1[m * 128 + h] * Wu1[h * 128 + o];
    T[m * 128 + o] = acc;
  }
}

// ---- prep2: C_sw = (T@W1)/sqrt(S) (128x256, KT=4); Wm0_sw (256x128, KT=8)
__global__ __launch_bounds__(256) void prep2(
    const float* __restrict__ T, const float* __restrict__ W1,
    const float* __restrict__ Wm0, unsigned short* __restrict__ C_sw,
    unsigned short* __restrict__ Wm0_sw) {
  int b = blockIdx.x, tid = threadIdx.x;
  if (b < 128) {
    int m = b, n = tid;
    float acc = 0.f;
    for (int h = 0; h < 128; ++h) acc += T[m * 128 + h] * W1[h * 256 + n];
    put_sw(C_sw, m, n, acc * 0.08838834764831845f, 4);
  } else {
    int k = (b - 128) * 2 + (tid >> 7);
    int n = tid & 127;
    put_sw(Wm0_sw, k, n, Wm0[k * 128 + n], 8);
  }
}

#define XV_S 136  // bf16 row stride, 48-row A matrices (pad 8 -> even banks)
#define XA_S 264  // bf16 row stride, 16x256 gate-A
#define GS_S 132  // f32 row stride, 16x128 gate
#define VO_S 260  // f32 row stride, 48x256 vo

__global__ __launch_bounds__(256, 2) void main_k(
    const float* __restrict__ x, const float* __restrict__ bm0,
    const unsigned short* __restrict__ Wcat_sw,
    const unsigned short* __restrict__ Wm0_sw,
    const unsigned short* __restrict__ C_sw, float* __restrict__ out) {
  // LDS overlay plan (62976 B total):
  //  [0,13056)        v1   48x136 bf16   (phase3 A)        alive: gating->phase3
  //  [13056,21504)    xa   16x264 bf16   ([s|vn] gate-A)   alive: load->gateGEMM
  //  [21504,34560)    xv   48x136 bf16   (phase1 A)        alive: load->phase1
  //  [34560,47616)    vh   48x136 bf16   (Vh0)             alive: phase1->norm
  //  [47616,56064)    gsm  16x132 f32    (gate)            alive: gate->gating
  //  [13056,62976)    vo   48x260 f32    overlays xa..gsm  alive: phase3->store
  __shared__ __align__(16) unsigned char smem[62976];
  unsigned short* v1 = (unsigned short*)smem;
  unsigned short* xa = (unsigned short*)(smem + 13056);
  unsigned short* xv = (unsigned short*)(smem + 21504);
  unsigned short* vh = (unsigned short*)(smem + 34560);
  float* gsm = (float*)(smem + 47616);
  float* vo = (float*)(smem + 13056);

  const int tid = threadIdx.x;
  const int lane = tid & 63;
  const int w = tid >> 6;
  const int l15 = lane & 15;
  const int quad = lane >> 4;
  const int r0 = blockIdx.x << 4;  // 16 rows per block
  const float* xrow = x + (size_t)r0 * 512;

  // ---- stage: 16 rows x 512 f32 -> xa (s, bf16) + xv ((3r+t)-major, bf16)
  for (int i = 0; i < 8; ++i) {
    int q = tid + 256 * i;  // float4 idx, 2048
    int r = q >> 7;
    int c4 = (q & 127) << 2;
    float4 v4 = *(const float4*)(xrow + r * 512 + c4);
    float vv[4] = {v4.x, v4.y, v4.z, v4.w};
#pragma unroll
    for (int e = 0; e < 4; ++e) {
      int c = c4 + e;
      if (c < 128) {
        xa[r * XA_S + c] = f2bf(vv[e]);
      } else {
        int cc = c - 128;
        int m = cc / 3, t = cc - 3 * m;
        xv[(3 * r + t) * XV_S + m] = f2bf(vv[e]);
      }
    }
  }
  __syncthreads();

  const int ntg[4] = {2 * w, 2 * w + 1, 8 + 2 * w, 9 + 2 * w};
  const floatx4 zf4 = {0.f, 0.f, 0.f, 0.f};

  // ---- phase1: [Vh|Vu] = xv(48x128) @ Wcat(128x256); wave w -> ntg cols
  floatx4 acc[3][4];
#pragma unroll
  for (int mt = 0; mt < 3; ++mt)
#pragma unroll
    for (int t = 0; t < 4; ++t) acc[mt][t] = zf4;
  for (int kt = 0; kt < 4; ++kt) {
    short8 bf[4], af[3];
#pragma unroll
    for (int t = 0; t < 4; ++t)
      bf[t] = *(const short8*)(Wcat_sw + (((ntg[t] * 4 + kt) * 64 + lane) << 3));
#pragma unroll
    for (int mt = 0; mt < 3; ++mt)
      af[mt] = *(const short8*)(xv + (mt * 16 + l15) * XV_S + kt * 32 + quad * 8);
#pragma unroll
    for (int mt = 0; mt < 3; ++mt)
#pragma unroll
      for (int t = 0; t < 4; ++t)
        acc[mt][t] = __builtin_amdgcn_mfma_f32_16x16x32_bf16(af[mt], bf[t],
                                                             acc[mt][t], 0, 0, 0);
  }
  // write Vh (ntg[0..1]) to LDS bf16; D-layout: row=quad*4+reg, col=l15
#pragma unroll
  for (int t = 0; t < 2; ++t)
#pragma unroll
    for (int mt = 0; mt < 3; ++mt)
#pragma unroll
      for (int rg = 0; rg < 4; ++rg) {
        int row = mt * 16 + quad * 4 + rg;
        int col = ntg[t] * 16 + l15;
        vh[row * XV_S + col] = f2bf(acc[mt][t][rg]);
      }
  __syncthreads();

  // ---- norms: vn[r][h] = sqrt(sum_t Vh^2 + eps) -> xa[:,128:]
  for (int i = 0; i < 8; ++i) {
    int e = tid + 256 * i;  // 2048
    int r = e >> 7, h = e & 127;
    float a0 = bf2f(vh[(3 * r) * XV_S + h]);
    float a1 = bf2f(vh[(3 * r + 1) * XV_S + h]);
    float a2 = bf2f(vh[(3 * r + 2) * XV_S + h]);
    xa[r * XA_S + 128 + h] = f2bf(sqrtf(a0 * a0 + a1 * a1 + a2 * a2 + 1e-8f));
  }
  __syncthreads();

  // ---- gate GEMM: sm = [s|vn](16x256) @ Wm0(256x128); wave w -> nt 2w,2w+1
  {
    floatx4 ga[2] = {zf4, zf4};
    for (int kt = 0; kt < 8; ++kt) {
      short8 af = *(const short8*)(xa + l15 * XA_S + kt * 32 + quad * 8);
      short8 b0 =
          *(const short8*)(Wm0_sw + ((((2 * w) * 8 + kt) * 64 + lane) << 3));
      short8 b1 =
          *(const short8*)(Wm0_sw + ((((2 * w + 1) * 8 + kt) * 64 + lane) << 3));
      ga[0] = __builtin_amdgcn_mfma_f32_16x16x32_bf16(af, b0, ga[0], 0, 0, 0);
      ga[1] = __builtin_amdgcn_mfma_f32_16x16x32_bf16(af, b1, ga[1], 0, 0, 0);
    }
#pragma unroll
    for (int t = 0; t < 2; ++t) {
      int col = (2 * w + t) * 16 + l15;
      float bias = bm0[col];
#pragma unroll
      for (int rg = 0; rg < 4; ++rg) {
        int row = quad * 4 + rg;  // molecule row in [0,16)
        float sm = ga[t][rg] + bias;
        gsm[row * GS_S + col] = 1.f / (1.f + __expf(-sm));
      }
    }
  }
  __syncthreads();

  // ---- gating: v1[ar][o] = Vu[ar][o] * g[ar/3][o]   (Vu = acc t=2,3)
#pragma unroll
  for (int t = 2; t < 4; ++t) {
    int o = (2 * w + (t - 2)) * 16 + l15;  // col within [0,128)
#pragma unroll
    for (int mt = 0; mt < 3; ++mt)
#pragma unroll
      for (int rg = 0; rg < 4; ++rg) {
        int ar = mt * 16 + quad * 4 + rg;
        float g = gsm[(ar / 3) * GS_S + o];
        v1[ar * XV_S + o] = f2bf(acc[mt][t][rg] * g);
      }
  }
  __syncthreads();

  // ---- phase3: vo = v1(48x128) @ C(128x256); wave w -> nt 4w..4w+3
#pragma unroll
  for (int mt = 0; mt < 3; ++mt)
#pragma unroll
    for (int t = 0; t < 4; ++t) acc[mt][t] = zf4;
  for (int kt = 0; kt < 4; ++kt) {
    short8 bf[4], af[3];
#pragma unroll
    for (int t = 0; t < 4; ++t)
      bf[t] =
          *(const short8*)(C_sw + ((((4 * w + t) * 4 + kt) * 64 + lane) << 3));
#pragma unroll
    for (int mt = 0; mt < 3; ++mt)
      af[mt] = *(const short8*)(v1 + (mt * 16 + l15) * XV_S + kt * 32 + quad * 8);
#pragma unroll
    for (int mt = 0; mt < 3; ++mt)
#pragma unroll
      for (int t = 0; t < 4; ++t)
        acc[mt][t] = __builtin_amdgcn_mfma_f32_16x16x32_bf16(af[mt], bf[t],
                                                             acc[mt][t], 0, 0, 0);
  }
  // write vo f32 to LDS (overlays dead xa/xv/vh/gsm; v1 untouched)
#pragma unroll
  for (int t = 0; t < 4; ++t)
#pragma unroll
    for (int mt = 0; mt < 3; ++mt)
#pragma unroll
      for (int rg = 0; rg < 4; ++rg) {
        int row = mt * 16 + quad * 4 + rg;
        int col = (4 * w + t) * 16 + l15;
        vo[row * VO_S + col] = acc[mt][t][rg];
      }
  __syncthreads();

  // ---- epilogue: per row 1024 f32 = 16 groups [16 zeros | 48 interleaved vo]
  float* orow = out + (size_t)r0 * 1024;
  for (int i = 0; i < 16; ++i) {
    int e = tid + 256 * i;  // float4 idx, 4096
    int r = e >> 8;
    int q4 = e & 255;
    int g = q4 >> 4, sub = q4 & 15;
    float4 val = make_float4(0.f, 0.f, 0.f, 0.f);
    if (sub >= 4) {
      float f[4];
#pragma unroll
      for (int ee = 0; ee < 4; ++ee) {
        int jj = sub * 4 + ee - 16;  // [0,48)
        int n = g * 16 + jj / 3;
        int t = jj - 3 * (jj / 3);
        f[ee] = vo[(3 * r + t) * VO_S + n];
      }
      val = make_float4(f[0], f[1], f[2], f[3]);
    }
    *(float4*)(orow + (size_t)r * 1024 + q4 * 4) = val;
  }
}

extern "C" void kernel_launch(void* const* d_in, const int* in_sizes, int n_in,
                              void* d_out, int out_size, void* d_ws,
                              size_t ws_size, hipStream_t stream) {
  const float* Wh0 = (const float*)d_in[1];
  const float* Wu0 = (const float*)d_in[2];
  const float* Wm0 = (const float*)d_in[3];
  const float* bm0 = (const float*)d_in[4];
  const float* Wh1 = (const float*)d_in[5];
  const float* Wu1 = (const float*)d_in[6];
  const float* W1 = (const float*)d_in[10];
  const float* mo = (const float*)d_in[0];

  unsigned short* ws = (unsigned short*)d_ws;
  unsigned short* Wcat_sw = ws;            // 32768 bf16 = 64 KB
  unsigned short* C_sw = ws + 32768;       // 64 KB
  unsigned short* Wm0_sw = ws + 65536;     // 64 KB
  float* T = (float*)(ws + 98304);         // 128x128 f32 = 64 KB

  prep1<<<256, 128, 0, stream>>>(Wh0, Wu0, Wh1, Wu1, Wcat_sw, T);
  prep2<<<256, 256, 0, stream>>>(T, W1, Wm0, C_sw, Wm0_sw);

  main_k<<<2048, 256, 0, stream>>>(mo, bm0, Wcat_sw, Wm0_sw, C_sw,
                                   (float*)d_out);
}

// Round 4
// 224.496 us; speedup vs baseline: 1.8475x; 1.0977x over previous
//
#include <hip/hip_runtime.h>
#include <hip/hip_bf16.h>

// E3TAOBackflow on MI355X — MFMA bf16, register-resident norms/gating.
// Reduction (verified R2/R3): antisymmetrization => scalar out = 0 exactly,
// vector out = (v @ [Wh0@Wu0]) * sigmoid([s,||v@Wh0||] @ Wm0 + bm0) @ C,
// C = Wh1@Wu1@W1/sqrt(S).  Wm1, bm1, W0 dead.  Output f32.
// t-split M: 3 GEMMs 16x128x256 sharing B-frags; cross-t norm and sigmoid
// gating stay in registers (D-layouts align); phase3 D stores directly to
// global as float3 (out col = nt*64 + 16 + 3*l15 + t). 3 barriers total.

typedef __attribute__((ext_vector_type(8))) short short8;
typedef __attribute__((ext_vector_type(4))) float floatx4;

static __device__ __forceinline__ unsigned short f2bf(float f) {
  unsigned u = __float_as_uint(f);
  u = (u + 0x7fffu + ((u >> 16) & 1u)) >> 16;  // RNE
  return (unsigned short)u;
}
static __device__ __forceinline__ unsigned pk2(float lo, float hi) {
  __hip_bfloat162 h = __float22bfloat162_rn(make_float2(lo, hi));
  return *(unsigned*)&h;  // low 16 = lo
}

// write element B[k][n] into swizzled fragment layout (KT = K/32)
static __device__ __forceinline__ void put_sw(unsigned short* B, int k, int n,
                                              float val, int KT) {
  int kt = k >> 5, quad = (k >> 3) & 3, j = k & 7;
  int nt = n >> 4, c = n & 15;
  int lane = quad * 16 + c;
  B[(((nt * KT + kt) * 64 + lane) << 3) + j] = f2bf(val);
}

// ---- prep1: Wcat = [Wh0 | Wh0@Wu0] -> Wcat_sw (128x256, KT=4); T = Wh1@Wu1
__global__ __launch_bounds__(128) void prep1(
    const float* __restrict__ Wh0, const float* __restrict__ Wu0,
    const float* __restrict__ Wh1, const float* __restrict__ Wu1,
    unsigned short* __restrict__ Wcat_sw, float* __restrict__ T) {
  int b = blockIdx.x, o = threadIdx.x;
  if (b < 128) {
    int m = b;
    float acc = 0.f;
    for (int h = 0; h < 128; ++h) acc += Wh0[m * 128 + h] * Wu0[h * 128 + o];
    put_sw(Wcat_sw, m, o, Wh0[m * 128 + o], 4);
    put_sw(Wcat_sw, m, o + 128, acc, 4);
  } else {
    int m = b - 128;
    float acc = 0.f;
    for (int h = 0; h < 128; ++h) acc += Wh1[m * 128 + h] * Wu1[h * 128 + o];
    T[m * 128 + o] = acc;
  }
}

// ---- prep2: C_sw = (T@W1)/sqrt(S) (128x256, KT=4); Wm0_sw (256x128, KT=8)
__global__ __launch_bounds__(256) void prep2(
    const float* __restrict__ T, const float* __restrict__ W1,
    const float* __restrict__ Wm0, unsigned short* __restrict__ C_sw,
    unsigned short* __restrict__ Wm0_sw) {
  int b = blockIdx.x, tid = threadIdx.x;
  if (b < 128) {
    int m = b, n = tid;
    float acc = 0.f;
    for (int h = 0; h < 128; ++h) acc += T[m * 128 + h] * W1[h * 256 + n];
    put_sw(C_sw, m, n, acc * 0.08838834764831845f, 4);
  } else {
    int k = (b - 128) * 2 + (tid >> 7);
    int n = tid & 127;
    put_sw(Wm0_sw, k, n, Wm0[k * 128 + n], 8);
  }
}

#define XA_S 264  // bf16 row stride for xa (256 + 8 pad; 528B = 33*16 ok)
#define XV_S 136  // bf16 row stride for xv/v1 (128 + 8 pad; 272B = 17*16 ok)
#define XV_T 2176 // elements per t-plane (16 * 136)

__global__ __launch_bounds__(256, 4) void main_k(
    const float* __restrict__ x, const float* __restrict__ bm0,
    const unsigned short* __restrict__ Wcat_sw,
    const unsigned short* __restrict__ Wm0_sw,
    const unsigned short* __restrict__ C_sw, float* __restrict__ out) {
  // LDS (34560 B): v1 [0,13056) | xa [13056,21504) | xv [21504,34560)
  __shared__ __align__(16) unsigned char smem[34560];
  unsigned short* v1 = (unsigned short*)smem;
  unsigned short* xa = (unsigned short*)(smem + 13056);
  unsigned short* xv = (unsigned short*)(smem + 21504);

  const int tid = threadIdx.x;
  const int lane = tid & 63;
  const int w = tid >> 6;
  const int l15 = lane & 15;
  const int quad = lane >> 4;
  const int r0 = blockIdx.x << 4;  // 16 rows/block
  const float* xrow = x + (size_t)r0 * 512;
  const int ntg[4] = {2 * w, 2 * w + 1, 8 + 2 * w, 9 + 2 * w};

  // bias for gate cols this lane will own (needed post-gate; load early)
  float bias0 = bm0[(2 * w) * 16 + l15];
  float bias1 = bm0[(2 * w + 1) * 16 + l15];

  // ---- stage: s -> xa bf16; v -> xv[t][r][m] bf16 (packed b64 writes)
#pragma unroll
  for (int i = 0; i < 2; ++i) {  // s: 512 float4 chunks
    int e = tid + 256 * i;
    int r = e >> 5, c0 = (e & 31) << 2;
    float4 s4 = *(const float4*)(xrow + r * 512 + c0);
    uint2 p = make_uint2(pk2(s4.x, s4.y), pk2(s4.z, s4.w));
    *(uint2*)(xa + r * XA_S + c0) = p;
  }
#pragma unroll
  for (int i = 0; i < 2; ++i) {  // v: 512 chunks of 12 floats (4 m x 3 t)
    int e = tid + 256 * i;
    int r = e >> 5, mc = e & 31;
    const float* p = xrow + r * 512 + 128 + mc * 12;
    float4 a = *(const float4*)(p);
    float4 b = *(const float4*)(p + 4);
    float4 c = *(const float4*)(p + 8);
    float f[12] = {a.x, a.y, a.z, a.w, b.x, b.y, b.z, b.w, c.x, c.y, c.z, c.w};
#pragma unroll
    for (int t = 0; t < 3; ++t) {
      uint2 pk = make_uint2(pk2(f[t], f[t + 3]), pk2(f[t + 6], f[t + 9]));
      *(uint2*)(xv + t * XV_T + r * XV_S + mc * 4) = pk;
    }
  }
  __syncthreads();  // B1

  const floatx4 zf4 = {0.f, 0.f, 0.f, 0.f};

  // ---- phase1: per t, [Vh|Vu](16x256) = xv_t(16x128) @ Wcat; B shared over t
  floatx4 acc[3][4];
#pragma unroll
  for (int t = 0; t < 3; ++t)
#pragma unroll
    for (int j = 0; j < 4; ++j) acc[t][j] = zf4;
  for (int kt = 0; kt < 4; ++kt) {
    short8 bf[4];
#pragma unroll
    for (int j = 0; j < 4; ++j)
      bf[j] = *(const short8*)(Wcat_sw + (((ntg[j] * 4 + kt) * 64 + lane) << 3));
#pragma unroll
    for (int t = 0; t < 3; ++t) {
      short8 af = *(const short8*)(xv + t * XV_T + l15 * XV_S + kt * 32 + quad * 8);
#pragma unroll
      for (int j = 0; j < 4; ++j)
        acc[t][j] = __builtin_amdgcn_mfma_f32_16x16x32_bf16(af, bf[j], acc[t][j], 0, 0, 0);
    }
  }

  // ---- norms in registers: vn = sqrt(sum_t Vh_t^2 + eps) -> xa[:,128:]
#pragma unroll
  for (int j = 0; j < 2; ++j)
#pragma unroll
    for (int rg = 0; rg < 4; ++rg) {
      float s0 = acc[0][j][rg], s1 = acc[1][j][rg], s2 = acc[2][j][rg];
      float vn = sqrtf(s0 * s0 + s1 * s1 + s2 * s2 + 1e-8f);
      int r = quad * 4 + rg;
      int h = ntg[j] * 16 + l15;
      xa[r * XA_S + 128 + h] = f2bf(vn);
    }
  __syncthreads();  // B2

  // ---- gate GEMM: sm(16x128) = [s|vn](16x256) @ Wm0; wave w -> cols 2w,2w+1
  floatx4 ga[2] = {zf4, zf4};
  for (int kt = 0; kt < 8; ++kt) {
    short8 af = *(const short8*)(xa + l15 * XA_S + kt * 32 + quad * 8);
    short8 b0 = *(const short8*)(Wm0_sw + ((((2 * w) * 8 + kt) * 64 + lane) << 3));
    short8 b1 = *(const short8*)(Wm0_sw + ((((2 * w + 1) * 8 + kt) * 64 + lane) << 3));
    ga[0] = __builtin_amdgcn_mfma_f32_16x16x32_bf16(af, b0, ga[0], 0, 0, 0);
    ga[1] = __builtin_amdgcn_mfma_f32_16x16x32_bf16(af, b1, ga[1], 0, 0, 0);
  }
  // sigmoid + gating in registers: gate D-layout == Vu acc layout (lane-exact)
  float g[2][4];
#pragma unroll
  for (int j = 0; j < 2; ++j) {
    float bias = j ? bias1 : bias0;
#pragma unroll
    for (int rg = 0; rg < 4; ++rg)
      g[j][rg] = 1.f / (1.f + __expf(-(ga[j][rg] + bias)));
  }
#pragma unroll
  for (int t = 0; t < 3; ++t)
#pragma unroll
    for (int j = 0; j < 2; ++j)
#pragma unroll
      for (int rg = 0; rg < 4; ++rg) {
        int r = quad * 4 + rg;
        int o = (2 * w + j) * 16 + l15;  // Vu col within [0,128)
        v1[t * XV_T + r * XV_S + o] = f2bf(acc[t][2 + j][rg] * g[j][rg]);
      }
  __syncthreads();  // B3

  // ---- phase3: per t, vo_t(16x256) = v1_t(16x128) @ C; B shared over t
  floatx4 vacc[3][4];
#pragma unroll
  for (int t = 0; t < 3; ++t)
#pragma unroll
    for (int j = 0; j < 4; ++j) vacc[t][j] = zf4;
  for (int kt = 0; kt < 4; ++kt) {
    short8 bf[4];
#pragma unroll
    for (int j = 0; j < 4; ++j)
      bf[j] = *(const short8*)(C_sw + (((ntg[j] * 4 + kt) * 64 + lane) << 3));
#pragma unroll
    for (int t = 0; t < 3; ++t) {
      short8 af = *(const short8*)(v1 + t * XV_T + l15 * XV_S + kt * 32 + quad * 8);
#pragma unroll
      for (int j = 0; j < 4; ++j)
        vacc[t][j] = __builtin_amdgcn_mfma_f32_16x16x32_bf16(af, bf[j], vacc[t][j], 0, 0, 0);
    }
  }

  // ---- epilogue: direct stores. Row layout: 16 groups of 64 = [16 zeros |
  // 48 data], data col = g*64 + 16 + 3*(n&15) + t with g = n>>4 = nt.
  float* orow = out + (size_t)r0 * 1024;
#pragma unroll
  for (int i = 0; i < 4; ++i) {  // zeros: 1024 float4
    int e = tid + 256 * i;
    int r = e >> 6, gblk = (e >> 2) & 15, s4 = e & 3;
    *(float4*)(orow + (size_t)r * 1024 + gblk * 64 + s4 * 4) =
        make_float4(0.f, 0.f, 0.f, 0.f);
  }
#pragma unroll
  for (int j = 0; j < 4; ++j) {
    int nt = ntg[j];
#pragma unroll
    for (int rg = 0; rg < 4; ++rg) {
      int r = quad * 4 + rg;
      *(float3*)(orow + (size_t)r * 1024 + nt * 64 + 16 + 3 * l15) =
          make_float3(vacc[0][j][rg], vacc[1][j][rg], vacc[2][j][rg]);
    }
  }
}

extern "C" void kernel_launch(void* const* d_in, const int* in_sizes, int n_in,
                              void* d_out, int out_size, void* d_ws,
                              size_t ws_size, hipStream_t stream) {
  const float* mo = (const float*)d_in[0];
  const float* Wh0 = (const float*)d_in[1];
  const float* Wu0 = (const float*)d_in[2];
  const float* Wm0 = (const float*)d_in[3];
  const float* bm0 = (const float*)d_in[4];
  const float* Wh1 = (const float*)d_in[5];
  const float* Wu1 = (const float*)d_in[6];
  const float* W1 = (const float*)d_in[10];
  // d_in[7]=Wm1, d_in[8]=bm1, d_in[9]=W0: dead under antisymmetrization

  unsigned short* ws = (unsigned short*)d_ws;
  unsigned short* Wcat_sw = ws;         // 64 KB
  unsigned short* C_sw = ws + 32768;    // 64 KB
  unsigned short* Wm0_sw = ws + 65536;  // 64 KB
  float* T = (float*)(ws + 98304);      // 64 KB

  prep1<<<256, 128, 0, stream>>>(Wh0, Wu0, Wh1, Wu1, Wcat_sw, T);
  prep2<<<256, 256, 0, stream>>>(T, W1, Wm0, C_sw, Wm0_sw);

  main_k<<<2048, 256, 0, stream>>>(mo, bm0, Wcat_sw, Wm0_sw, C_sw,
                                   (float*)d_out);
}